// Round 2
// baseline (131.888 us; speedup 1.0000x reference)
//
#include <hip/hip_runtime.h>

// Problem constants
#define NROWS 1024
#define DIMX  256
#define HIDX  512

// ws layout in floats:
//   [0,256)                 : colmean(P)
//   [256,512)               : colmean(G)
//   [512, 512+1024*512)     : Hid1 = relu(H@W1+b1)            (2 MB)
//   next 1024*512           : Hidg = relu([H|P]@W1g+b1g)      (2 MB)
//   next 256                : per-block partial sums
#define WS_EP   0
#define WS_EG   256
#define WS_HID1 512
#define WS_HIDG (512 + NROWS * HIDX)
#define WS_PART (512 + 2 * NROWS * HIDX)

// ---------------------------------------------------------------------------
// Kernel 1: column means of P and G. grid=2 blocks, 1024 threads.
// thread d of chunk c sums rows [c*256, c*256+256) of column d.
__global__ __launch_bounds__(1024) void colmean_kernel(const float* __restrict__ P,
                                                       const float* __restrict__ G,
                                                       float* __restrict__ ws)
{
    const float* M = blockIdx.x ? G : P;
    const int d = threadIdx.x & (DIMX - 1);
    const int chunk = threadIdx.x >> 8; // 0..3
    const float* p = M + (size_t)chunk * 256 * DIMX + d;
    float s0 = 0.f, s1 = 0.f, s2 = 0.f, s3 = 0.f;
    #pragma unroll 4
    for (int j = 0; j < 256; j += 4) {
        s0 += p[(size_t)(j + 0) * DIMX];
        s1 += p[(size_t)(j + 1) * DIMX];
        s2 += p[(size_t)(j + 2) * DIMX];
        s3 += p[(size_t)(j + 3) * DIMX];
    }
    __shared__ float red[1024];
    red[threadIdx.x] = (s0 + s1) + (s2 + s3);
    __syncthreads();
    if (threadIdx.x < DIMX) {
        float t = (red[d] + red[DIMX + d]) + (red[2 * DIMX + d] + red[3 * DIMX + d]);
        ws[(blockIdx.x ? WS_EG : WS_EP) + d] = t * (1.0f / NROWS);
    }
}

// ---------------------------------------------------------------------------
// K=256 fp32 GEMM pass: acc[4][4] += A[mbase+r][k] * Wn[k*HIDX + c]
// A has row stride DIMX. Wn is the weight pointer already offset to column n.
__device__ __forceinline__ void gemm_pass_256(const float* __restrict__ A,
                                              const float* __restrict__ Wn,
                                              float (&acc)[4][4], int mbase)
{
    #pragma unroll 2
    for (int k = 0; k < 256; k += 4) {
        float a[4][4];
        #pragma unroll
        for (int r = 0; r < 4; ++r) {
            float4 v = *(const float4*)(A + (size_t)(mbase + r) * DIMX + k);
            a[r][0] = v.x; a[r][1] = v.y; a[r][2] = v.z; a[r][3] = v.w;
        }
        #pragma unroll
        for (int j = 0; j < 4; ++j) {
            float4 w = *(const float4*)(Wn + (size_t)(k + j) * HIDX);
            #pragma unroll
            for (int r = 0; r < 4; ++r) {
                acc[r][0] += a[r][j] * w.x;
                acc[r][1] += a[r][j] * w.y;
                acc[r][2] += a[r][j] * w.z;
                acc[r][3] += a[r][j] * w.w;
            }
        }
    }
}

// ---------------------------------------------------------------------------
// Kernel 2: hidden layers for both MLPs.
// grid = 256 blocks: [0,128) -> MLP1 (Hid1), [128,256) -> MLPg (Hidg).
// Block tile 64 rows x 64 hidden cols; 256 threads; 4x4 outputs/thread.
__global__ __launch_bounds__(256) void hidden_kernel(const float* __restrict__ H,
                                                     const float* __restrict__ P,
                                                     const float* __restrict__ W1,
                                                     const float* __restrict__ b1,
                                                     const float* __restrict__ W1g,
                                                     const float* __restrict__ b1g,
                                                     float* __restrict__ ws)
{
    const int bx  = blockIdx.x;
    const int mlp = bx >> 7;
    const int bi  = bx & 127;
    const int m0  = (bi >> 3) * 64;   // 16 row tiles
    const int n0  = (bi & 7) * 64;    // 8 col tiles (512 hidden)
    const int t   = threadIdx.x;
    const int tx  = t & 15, ty = t >> 4;
    const int n     = n0 + tx * 4;
    const int mbase = m0 + ty * 4;

    const float* W  = mlp ? W1g : W1;
    const float* bb = mlp ? b1g : b1;
    float* out = ws + (mlp ? WS_HIDG : WS_HID1);

    float acc[4][4] = {};
    // first 256 K: histology rows of the weight
    gemm_pass_256(H, W + n, acc, mbase);
    // MLPg: second 256 K from pathways, weight rows 256..511
    if (mlp) {
        gemm_pass_256(P, W + (size_t)256 * HIDX + n, acc, mbase);
    }

    const float4 bv = *(const float4*)(bb + n);
    #pragma unroll
    for (int r = 0; r < 4; ++r) {
        float4 v;
        v.x = fmaxf(acc[r][0] + bv.x, 0.f);
        v.y = fmaxf(acc[r][1] + bv.y, 0.f);
        v.z = fmaxf(acc[r][2] + bv.z, 0.f);
        v.w = fmaxf(acc[r][3] + bv.w, 0.f);
        *(float4*)(out + (size_t)(mbase + r) * HIDX + n) = v;
    }
}

// ---------------------------------------------------------------------------
// Kernel 3: mu-tile = Hid @ W2, immediately dotted with (Y - colmean(Y)).
// grid = 256 blocks: [0,128) -> MLP1 vs P, [128,256) -> MLPg vs G.
// Block tile 64 rows x 32 out cols; 256 threads; 4x2 outputs/thread.
// b2 provably contributes zero (centered Y) and is skipped.
__global__ __launch_bounds__(256) void out_reduce_kernel(const float* __restrict__ P,
                                                         const float* __restrict__ G,
                                                         const float* __restrict__ W2,
                                                         const float* __restrict__ W2g,
                                                         float* __restrict__ ws)
{
    const int bx  = blockIdx.x;
    const int mlp = bx >> 7;
    const int bi  = bx & 127;
    const int m0  = (bi >> 3) * 64;  // 16 row tiles
    const int n0  = (bi & 7) * 32;   // 8 col tiles (256 out dims)
    const int t   = threadIdx.x;
    const int tx  = t & 15, ty = t >> 4;
    const int n     = n0 + tx * 2;
    const int mbase = m0 + ty * 4;

    const float* Hd = ws + (mlp ? WS_HIDG : WS_HID1);
    const float* Wn = (mlp ? W2g : W2) + n;
    const float* Y  = mlp ? G : P;
    const float* E  = ws + (mlp ? WS_EG : WS_EP);

    float acc[4][2] = {};
    #pragma unroll 2
    for (int k = 0; k < HIDX; k += 4) {
        float a[4][4];
        #pragma unroll
        for (int r = 0; r < 4; ++r) {
            float4 v = *(const float4*)(Hd + (size_t)(mbase + r) * HIDX + k);
            a[r][0] = v.x; a[r][1] = v.y; a[r][2] = v.z; a[r][3] = v.w;
        }
        #pragma unroll
        for (int j = 0; j < 4; ++j) {
            float2 w = *(const float2*)(Wn + (size_t)(k + j) * DIMX);
            #pragma unroll
            for (int r = 0; r < 4; ++r) {
                acc[r][0] += a[r][j] * w.x;
                acc[r][1] += a[r][j] * w.y;
            }
        }
    }

    const float e0 = E[n], e1 = E[n + 1];
    float part = 0.f;
    #pragma unroll
    for (int r = 0; r < 4; ++r) {
        float2 y = *(const float2*)(Y + (size_t)(mbase + r) * DIMX + n);
        part += acc[r][0] * (y.x - e0) + acc[r][1] * (y.y - e1);
    }

    __shared__ float red[256];
    red[t] = part;
    __syncthreads();
    #pragma unroll
    for (int s = 128; s > 0; s >>= 1) {
        if (t < s) red[t] += red[t + s];
        __syncthreads();
    }
    if (t == 0) ws[WS_PART + bx] = red[0];
}

// ---------------------------------------------------------------------------
// Kernel 4: final reduce of 256 partials in double, scale by 1/N.
__global__ __launch_bounds__(256) void final_kernel(const float* __restrict__ ws,
                                                    float* __restrict__ out)
{
    const int t = threadIdx.x;
    __shared__ double red[256];
    red[t] = (double)ws[WS_PART + t];
    __syncthreads();
    #pragma unroll
    for (int s = 128; s > 0; s >>= 1) {
        if (t < s) red[t] += red[t + s];
        __syncthreads();
    }
    if (t == 0) out[0] = (float)(red[0] * (1.0 / NROWS));
}

// ---------------------------------------------------------------------------
extern "C" void kernel_launch(void* const* d_in, const int* in_sizes, int n_in,
                              void* d_out, int out_size, void* d_ws, size_t ws_size,
                              hipStream_t stream)
{
    const float* H   = (const float*)d_in[0];   // histology   [1024,256]
    const float* P   = (const float*)d_in[1];   // pathways    [1024,256]
    const float* G   = (const float*)d_in[2];   // global_embed[1024,256]
    const float* W1  = (const float*)d_in[3];   // [256,512]
    const float* b1  = (const float*)d_in[4];   // [512]
    const float* W2  = (const float*)d_in[5];   // [512,256]
    // d_in[6] = b2   : provably zero contribution, unused
    const float* W1g = (const float*)d_in[7];   // [512,512]
    const float* b1g = (const float*)d_in[8];   // [512]
    const float* W2g = (const float*)d_in[9];   // [512,256]
    // d_in[10] = b2g : unused
    float* ws  = (float*)d_ws;
    float* out = (float*)d_out;

    hipLaunchKernelGGL(colmean_kernel,    dim3(2),   dim3(1024), 0, stream, P, G, ws);
    hipLaunchKernelGGL(hidden_kernel,     dim3(256), dim3(256),  0, stream, H, P, W1, b1, W1g, b1g, ws);
    hipLaunchKernelGGL(out_reduce_kernel, dim3(256), dim3(256),  0, stream, P, G, W2, W2g, ws);
    hipLaunchKernelGGL(final_kernel,      dim3(1),   dim3(256),  0, stream, ws, out);
}

// Round 3
// 105.594 us; speedup vs baseline: 1.2490x; 1.2490x over previous
//
#include <hip/hip_runtime.h>

// Problem constants
#define NROWS 1024
#define DIMX  256
#define HIDX  512

// ws layout in floats:
//   [0, 8192)            : colmean partials: [mat(2)][stripe(16)][col(256)]
//   [8192, +512K)        : Hid1 = relu(H@W1+b1)          (2 MB)
//   next 512K            : Hidg = relu([H|P]@W1g+b1g)    (2 MB)
//   next 512             : per-block partial sums from out_reduce
#define WS_CM   0
#define WS_HID1 8192
#define WS_HIDG (8192 + NROWS * HIDX)
#define WS_PART (8192 + 2 * NROWS * HIDX)

// ---------------------------------------------------------------------------
// Core dot: 4 output columns, one input row. Row pointer Arow (contiguous K),
// weight pointer Wn pre-offset to column n, row stride LDW. K-step 8 for ILP.
template<int LDW, int KLEN>
__device__ __forceinline__ void dot4(const float* __restrict__ Arow,
                                     const float* __restrict__ Wn,
                                     float (&acc)[4])
{
    #pragma unroll 2
    for (int k = 0; k < KLEN; k += 8) {
        const float4 a0 = *(const float4*)(Arow + k);
        const float4 a1 = *(const float4*)(Arow + k + 4);
        const float4 w0 = *(const float4*)(Wn + (size_t)(k + 0) * LDW);
        const float4 w1 = *(const float4*)(Wn + (size_t)(k + 1) * LDW);
        const float4 w2 = *(const float4*)(Wn + (size_t)(k + 2) * LDW);
        const float4 w3 = *(const float4*)(Wn + (size_t)(k + 3) * LDW);
        const float4 w4 = *(const float4*)(Wn + (size_t)(k + 4) * LDW);
        const float4 w5 = *(const float4*)(Wn + (size_t)(k + 5) * LDW);
        const float4 w6 = *(const float4*)(Wn + (size_t)(k + 6) * LDW);
        const float4 w7 = *(const float4*)(Wn + (size_t)(k + 7) * LDW);
        acc[0] += a0.x * w0.x; acc[1] += a0.x * w0.y; acc[2] += a0.x * w0.z; acc[3] += a0.x * w0.w;
        acc[0] += a0.y * w1.x; acc[1] += a0.y * w1.y; acc[2] += a0.y * w1.z; acc[3] += a0.y * w1.w;
        acc[0] += a0.z * w2.x; acc[1] += a0.z * w2.y; acc[2] += a0.z * w2.z; acc[3] += a0.z * w2.w;
        acc[0] += a0.w * w3.x; acc[1] += a0.w * w3.y; acc[2] += a0.w * w3.z; acc[3] += a0.w * w3.w;
        acc[0] += a1.x * w4.x; acc[1] += a1.x * w4.y; acc[2] += a1.x * w4.z; acc[3] += a1.x * w4.w;
        acc[0] += a1.y * w5.x; acc[1] += a1.y * w5.y; acc[2] += a1.y * w5.z; acc[3] += a1.y * w5.w;
        acc[0] += a1.z * w6.x; acc[1] += a1.z * w6.y; acc[2] += a1.z * w6.z; acc[3] += a1.z * w6.w;
        acc[0] += a1.w * w7.x; acc[1] += a1.w * w7.y; acc[2] += a1.w * w7.z; acc[3] += a1.w * w7.w;
    }
}

// ---------------------------------------------------------------------------
// Kernel 1: hidden layers for both MLPs + colmean partials (fused launch).
// blocks [0,512)    : MLP1  Hid1 tile 16 rows x 64 cols (1x4 per thread)
// blocks [512,1024) : MLPg  Hidg tile 16 rows x 64 cols
// blocks [1024,1056): column-sum partials of P (16 stripes) and G (16 stripes)
__global__ __launch_bounds__(256) void hidden_colmean_kernel(
    const float* __restrict__ H, const float* __restrict__ P,
    const float* __restrict__ G,
    const float* __restrict__ W1, const float* __restrict__ b1,
    const float* __restrict__ W1g, const float* __restrict__ b1g,
    float* __restrict__ ws)
{
    const int bx = blockIdx.x;
    const int t  = threadIdx.x;

    if (bx >= 1024) {
        // column-sum partial: 64 rows of one matrix, thread t = column t
        const int cb = bx - 1024;                 // 0..31
        const float* M = (cb & 16) ? G : P;       // mat = cb>>4
        const int stripe = cb & 15;
        const float* p = M + (size_t)stripe * 64 * DIMX + t;
        float s0 = 0.f, s1 = 0.f, s2 = 0.f, s3 = 0.f;
        #pragma unroll 4
        for (int r = 0; r < 64; r += 4) {
            s0 += p[(r + 0) * DIMX];
            s1 += p[(r + 1) * DIMX];
            s2 += p[(r + 2) * DIMX];
            s3 += p[(r + 3) * DIMX];
        }
        ws[WS_CM + (cb >> 4) * 4096 + stripe * 256 + t] = (s0 + s1) + (s2 + s3);
        return;
    }

    const int mlp = bx >> 9;
    const int bi  = bx & 511;
    const int m0  = (bi >> 3) * 16;   // 64 row tiles of 16
    const int n0  = (bi & 7) * 64;    // 8 col tiles of 64
    const int tx  = t & 15, ty = t >> 4;
    const int n   = n0 + tx * 4;
    const int row = m0 + ty;

    const float* W  = mlp ? W1g : W1;
    const float* bb = mlp ? b1g : b1;
    float* out = ws + (mlp ? WS_HIDG : WS_HID1);

    float acc[4] = {0.f, 0.f, 0.f, 0.f};
    dot4<HIDX, 256>(H + (size_t)row * DIMX, W + n, acc);
    if (mlp) {
        dot4<HIDX, 256>(P + (size_t)row * DIMX, W + (size_t)256 * HIDX + n, acc);
    }

    const float4 bv = *(const float4*)(bb + n);
    float4 v;
    v.x = fmaxf(acc[0] + bv.x, 0.f);
    v.y = fmaxf(acc[1] + bv.y, 0.f);
    v.z = fmaxf(acc[2] + bv.z, 0.f);
    v.w = fmaxf(acc[3] + bv.w, 0.f);
    *(float4*)(out + (size_t)row * HIDX + n) = v;
}

// ---------------------------------------------------------------------------
// Kernel 2: mu = Hid @ W2 (b2 contributes exactly 0), dotted on the fly with
// (Y - colmean(Y)); per-block partial -> ws[WS_PART + bx].
// blocks [0,256): MLP1 vs P; [256,512): MLPg vs G. Tile 16 rows x 64 cols.
__global__ __launch_bounds__(256) void out_reduce_kernel(
    const float* __restrict__ P, const float* __restrict__ G,
    const float* __restrict__ W2, const float* __restrict__ W2g,
    float* __restrict__ ws)
{
    const int bx  = blockIdx.x;
    const int mlp = bx >> 8;
    const int bi  = bx & 255;
    const int m0  = (bi >> 2) * 16;  // 64 row tiles of 16
    const int n0  = (bi & 3) * 64;   // 4 col tiles of 64 (256 out dims)
    const int t   = threadIdx.x;
    const int tx  = t & 15, ty = t >> 4;
    const int n   = n0 + tx * 4;
    const int row = m0 + ty;

    const float* Hd = ws + (mlp ? WS_HIDG : WS_HID1);
    const float* Wn = (mlp ? W2g : W2) + n;
    const float* Y  = mlp ? G : P;

    float acc[4] = {0.f, 0.f, 0.f, 0.f};
    dot4<DIMX, HIDX>(Hd + (size_t)row * HIDX, Wn, acc);

    // combine colmean partials for this thread's 4 columns
    const float* cm = ws + WS_CM + mlp * 4096 + n;
    float4 e = {0.f, 0.f, 0.f, 0.f};
    #pragma unroll
    for (int s = 0; s < 16; ++s) {
        const float4 c = *(const float4*)(cm + s * 256);
        e.x += c.x; e.y += c.y; e.z += c.z; e.w += c.w;
    }
    const float inv = 1.0f / NROWS;

    const float4 y = *(const float4*)(Y + (size_t)row * DIMX + n);
    float part = acc[0] * (y.x - e.x * inv) + acc[1] * (y.y - e.y * inv)
               + acc[2] * (y.z - e.z * inv) + acc[3] * (y.w - e.w * inv);

    __shared__ float red[256];
    red[t] = part;
    __syncthreads();
    #pragma unroll
    for (int s = 128; s > 0; s >>= 1) {
        if (t < s) red[t] += red[t + s];
        __syncthreads();
    }
    if (t == 0) ws[WS_PART + bx] = red[0];
}

// ---------------------------------------------------------------------------
// Kernel 3: final reduce of 512 partials in double, scale by 1/N.
__global__ __launch_bounds__(256) void final_kernel(const float* __restrict__ ws,
                                                    float* __restrict__ out)
{
    const int t = threadIdx.x;
    __shared__ double red[256];
    red[t] = (double)ws[WS_PART + t] + (double)ws[WS_PART + 256 + t];
    __syncthreads();
    #pragma unroll
    for (int s = 128; s > 0; s >>= 1) {
        if (t < s) red[t] += red[t + s];
        __syncthreads();
    }
    if (t == 0) out[0] = (float)(red[0] * (1.0 / NROWS));
}

// ---------------------------------------------------------------------------
extern "C" void kernel_launch(void* const* d_in, const int* in_sizes, int n_in,
                              void* d_out, int out_size, void* d_ws, size_t ws_size,
                              hipStream_t stream)
{
    const float* H   = (const float*)d_in[0];   // histology   [1024,256]
    const float* P   = (const float*)d_in[1];   // pathways    [1024,256]
    const float* G   = (const float*)d_in[2];   // global_embed[1024,256]
    const float* W1  = (const float*)d_in[3];   // [256,512]
    const float* b1  = (const float*)d_in[4];   // [512]
    const float* W2  = (const float*)d_in[5];   // [512,256]
    // d_in[6] = b2   : provably zero contribution, unused
    const float* W1g = (const float*)d_in[7];   // [512,512]
    const float* b1g = (const float*)d_in[8];   // [512]
    const float* W2g = (const float*)d_in[9];   // [512,256]
    // d_in[10] = b2g : unused
    float* ws  = (float*)d_ws;
    float* out = (float*)d_out;

    hipLaunchKernelGGL(hidden_colmean_kernel, dim3(1056), dim3(256), 0, stream,
                       H, P, G, W1, b1, W1g, b1g, ws);
    hipLaunchKernelGGL(out_reduce_kernel,     dim3(512),  dim3(256), 0, stream,
                       P, G, W2, W2g, ws);
    hipLaunchKernelGGL(final_kernel,          dim3(1),    dim3(256), 0, stream,
                       ws, out);
}

// Round 4
// 48.709 us; speedup vs baseline: 2.7077x; 2.1679x over previous
//
#include <hip/hip_runtime.h>

// Problem constants
#define NROWS 1024
#define DIMX  256
#define HIDX  512

// ws layout in floats:
//   [0, 8192)     : colmean partials [mat(2)][stripe(16)][col(256)]
//   [8192, +512K) : Hid1 = relu(H@W1+b1)         (2 MB)
//   next 512K     : Hidg = relu([H|P]@W1g+b1g)   (2 MB)
//   next 256      : per-block partials from out_reduce
#define WS_CM   0
#define WS_HID1 8192
#define WS_HIDG (8192 + NROWS * HIDX)
#define WS_PART (8192 + 2 * NROWS * HIDX)

#define GLDS16(gp, lp) __builtin_amdgcn_global_load_lds(                     \
    (const __attribute__((address_space(1))) void*)(gp),                     \
    (__attribute__((address_space(3))) void*)(lp), 16, 0, 0)

// ---------------------------------------------------------------------------
// Stage a 64x64 fp32 tile M[r0..r0+64, c0..c0+64] (row stride ld floats) into
// LDS as row-major [64][64]. 16 chunks of 1 KB (4 tile rows each); 4 waves x 4
// global_load_lds. LDS dst is wave-uniform base (HW adds lane*16).
// SWZ (A-side): row r's 16B-chunk q holds global chunk q ^ ((r>>2)&3), done by
// permuting the per-lane GLOBAL source (LDS dst must stay linear). This makes
// the compute-side 4-distinct-row b128 reads hit 4 distinct bank quads.
template<bool SWZ>
__device__ __forceinline__ void stage_tile(const float* M, int r0, int c0,
                                           int ld, float* lds, int wv, int ln)
{
    const int rch = ln >> 4;   // row within 4-row chunk
    const int q   = ln & 15;   // 16B chunk within 256B row
    #pragma unroll
    for (int i = 0; i < 4; ++i) {
        const int c  = wv * 4 + i;                 // chunk id 0..15
        const int gq = SWZ ? (q ^ (c & 3)) : q;    // pre-swizzled source
        const float* gp = M + (size_t)(r0 + c * 4 + rch) * ld + c0 + gq * 4;
        GLDS16(gp, lds + c * 256);
    }
}

// ---------------------------------------------------------------------------
// 4x4 register-tile MAC over one 64-k LDS tile pair.
// A_lds swizzled per stage_tile<true>: G-chunk (kk>>2) lives at (kk>>2)^(ty&3).
__device__ __forceinline__ void mac_tile(const float* __restrict__ Al,
                                         const float* __restrict__ Wl,
                                         float (&acc)[4][4], int tx, int ty)
{
    const int sw = ty & 3;
    #pragma unroll
    for (int kk = 0; kk < 64; kk += 4) {
        const int ka = (kk >> 2) ^ sw;
        float a[4][4];   // [r][k]
        #pragma unroll
        for (int r = 0; r < 4; ++r) {
            const float4 v = *(const float4*)(Al + (ty * 4 + r) * 64 + ka * 4);
            a[r][0] = v.x; a[r][1] = v.y; a[r][2] = v.z; a[r][3] = v.w;
        }
        float w[4][4];   // [k][c]
        #pragma unroll
        for (int j = 0; j < 4; ++j) {
            const float4 v = *(const float4*)(Wl + (kk + j) * 64 + tx * 4);
            w[j][0] = v.x; w[j][1] = v.y; w[j][2] = v.z; w[j][3] = v.w;
        }
        #pragma unroll
        for (int r = 0; r < 4; ++r)
            #pragma unroll
            for (int j = 0; j < 4; ++j)
                acc[r][j] += a[r][0] * w[0][j] + a[r][1] * w[1][j]
                           + a[r][2] * w[2][j] + a[r][3] * w[3][j];
    }
}

// ---------------------------------------------------------------------------
// Kernel 1: hidden layers (LDS-staged GEMM) + colmean partials.
// blocks [0,128)   : MLP1  tile 64x64 of relu(H@W1+b1)        K=256
// blocks [128,256) : MLPg  tile 64x64 of relu([H|P]@W1g+b1g)  K=512
// blocks [256,288) : column-sum partials of P and G (16 stripes each)
__global__ __launch_bounds__(256) void hidden_colmean_kernel(
    const float* __restrict__ H, const float* __restrict__ P,
    const float* __restrict__ G,
    const float* __restrict__ W1, const float* __restrict__ b1,
    const float* __restrict__ W1g, const float* __restrict__ b1g,
    float* __restrict__ ws)
{
    __shared__ float As[2][64 * 64];
    __shared__ float Bs[2][64 * 64];

    const int bx = blockIdx.x;
    const int t  = threadIdx.x;

    if (bx >= 256) {  // colmean partial: 64 rows of one matrix, col = t
        const int cb = bx - 256;                  // 0..31
        const float* M = (cb & 16) ? G : P;
        const int stripe = cb & 15;
        const float* p = M + (size_t)stripe * 64 * DIMX + t;
        float s0 = 0.f, s1 = 0.f, s2 = 0.f, s3 = 0.f;
        #pragma unroll 4
        for (int r = 0; r < 64; r += 4) {
            s0 += p[(r + 0) * DIMX];
            s1 += p[(r + 1) * DIMX];
            s2 += p[(r + 2) * DIMX];
            s3 += p[(r + 3) * DIMX];
        }
        ws[WS_CM + (cb >> 4) * 4096 + stripe * 256 + t] = (s0 + s1) + (s2 + s3);
        return;
    }

    const int mlp = bx >> 7;
    const int bi  = bx & 127;
    const int m0  = (bi >> 3) * 64;   // 16 row tiles
    const int n0  = (bi & 7) * 64;    // 8 col tiles
    const int tx = t & 15, ty = t >> 4;
    const int wv = t >> 6, ln = t & 63;

    const float* Wm = mlp ? W1g : W1;
    const float* bb = mlp ? b1g : b1;
    float* out = ws + (mlp ? WS_HIDG : WS_HID1);
    const int nk = mlp ? 8 : 4;       // 64-k steps

    // prologue
    stage_tile<true >(H,  m0, 0,  DIMX, As[0], wv, ln);
    stage_tile<false>(Wm, 0,  n0, HIDX, Bs[0], wv, ln);
    asm volatile("s_waitcnt vmcnt(0)" ::: "memory");
    __syncthreads();

    float acc[4][4] = {};
    int buf = 0;
    for (int s = 0; s < nk; ++s) {
        if (s + 1 < nk) {
            const int k0 = (s + 1) * 64;
            const float* Asrc = (k0 < 256) ? H : P;     // concat [H|P] for MLPg
            const int    ac   = (k0 < 256) ? k0 : k0 - 256;
            stage_tile<true >(Asrc, m0, ac, DIMX, As[buf ^ 1], wv, ln);
            stage_tile<false>(Wm,   k0, n0, HIDX, Bs[buf ^ 1], wv, ln);
        }
        mac_tile(As[buf], Bs[buf], acc, tx, ty);
        asm volatile("s_waitcnt vmcnt(0)" ::: "memory");
        __syncthreads();
        buf ^= 1;
    }

    const float4 bv = *(const float4*)(bb + n0 + tx * 4);
    #pragma unroll
    for (int r = 0; r < 4; ++r) {
        float4 v;
        v.x = fmaxf(acc[r][0] + bv.x, 0.f);
        v.y = fmaxf(acc[r][1] + bv.y, 0.f);
        v.z = fmaxf(acc[r][2] + bv.z, 0.f);
        v.w = fmaxf(acc[r][3] + bv.w, 0.f);
        *(float4*)(out + (size_t)(m0 + ty * 4 + r) * HIDX + n0 + tx * 4) = v;
    }
}

// ---------------------------------------------------------------------------
// Kernel 2: mu-tile = Hid @ W2 (b2 contributes exactly 0), dotted on the fly
// with (Y - colmean(Y)). K-split x2 (legal: the Y-dot is linear in k).
// 256 blocks: bx = [mlp:1][ksplit:1][rowtile:4][coltile:2]; tile 64x64.
__global__ __launch_bounds__(256) void out_reduce_kernel(
    const float* __restrict__ P, const float* __restrict__ G,
    const float* __restrict__ W2, const float* __restrict__ W2g,
    float* __restrict__ ws)
{
    __shared__ float As[2][64 * 64];
    __shared__ float Bs[2][64 * 64];
    __shared__ float red[256];

    const int bx  = blockIdx.x;
    const int mlp = bx >> 7;
    const int ks  = (bx >> 6) & 1;
    const int m0  = ((bx >> 2) & 15) * 64;
    const int n0  = (bx & 3) * 64;
    const int kb  = ks * 256;
    const int t  = threadIdx.x;
    const int tx = t & 15, ty = t >> 4;
    const int wv = t >> 6, ln = t & 63;

    const float* Hd = ws + (mlp ? WS_HIDG : WS_HID1);
    const float* Wm = mlp ? W2g : W2;
    const float* Y  = mlp ? G : P;

    stage_tile<true >(Hd, m0, kb, HIDX, As[0], wv, ln);
    stage_tile<false>(Wm, kb, n0, DIMX, Bs[0], wv, ln);
    asm volatile("s_waitcnt vmcnt(0)" ::: "memory");
    __syncthreads();

    float acc[4][4] = {};
    int buf = 0;
    for (int s = 0; s < 4; ++s) {
        if (s + 1 < 4) {
            const int k0 = kb + (s + 1) * 64;
            stage_tile<true >(Hd, m0, k0, HIDX, As[buf ^ 1], wv, ln);
            stage_tile<false>(Wm, k0, n0, DIMX, Bs[buf ^ 1], wv, ln);
        }
        mac_tile(As[buf], Bs[buf], acc, tx, ty);
        asm volatile("s_waitcnt vmcnt(0)" ::: "memory");
        __syncthreads();
        buf ^= 1;
    }

    // colmean for this thread's 4 output columns
    const float* cm = ws + WS_CM + mlp * 4096 + n0 + tx * 4;
    float e0 = 0.f, e1 = 0.f, e2 = 0.f, e3 = 0.f;
    #pragma unroll
    for (int sp = 0; sp < 16; ++sp) {
        const float4 c4 = *(const float4*)(cm + sp * 256);
        e0 += c4.x; e1 += c4.y; e2 += c4.z; e3 += c4.w;
    }
    const float inv = 1.0f / NROWS;
    e0 *= inv; e1 *= inv; e2 *= inv; e3 *= inv;

    float part = 0.f;
    #pragma unroll
    for (int r = 0; r < 4; ++r) {
        const float4 y = *(const float4*)(Y + (size_t)(m0 + ty * 4 + r) * DIMX + n0 + tx * 4);
        part += acc[r][0] * (y.x - e0) + acc[r][1] * (y.y - e1)
              + acc[r][2] * (y.z - e2) + acc[r][3] * (y.w - e3);
    }

    red[t] = part;
    __syncthreads();
    #pragma unroll
    for (int sft = 128; sft > 0; sft >>= 1) {
        if (t < sft) red[t] += red[t + sft];
        __syncthreads();
    }
    if (t == 0) ws[WS_PART + bx] = red[0];
}

// ---------------------------------------------------------------------------
// Kernel 3: final reduce of 256 partials in double, scale by 1/N.
__global__ __launch_bounds__(256) void final_kernel(const float* __restrict__ ws,
                                                    float* __restrict__ out)
{
    const int t = threadIdx.x;
    __shared__ double red[256];
    red[t] = (double)ws[WS_PART + t];
    __syncthreads();
    #pragma unroll
    for (int s = 128; s > 0; s >>= 1) {
        if (t < s) red[t] += red[t + s];
        __syncthreads();
    }
    if (t == 0) out[0] = (float)(red[0] * (1.0 / NROWS));
}

// ---------------------------------------------------------------------------
extern "C" void kernel_launch(void* const* d_in, const int* in_sizes, int n_in,
                              void* d_out, int out_size, void* d_ws, size_t ws_size,
                              hipStream_t stream)
{
    const float* H   = (const float*)d_in[0];   // histology   [1024,256]
    const float* P   = (const float*)d_in[1];   // pathways    [1024,256]
    const float* G   = (const float*)d_in[2];   // global_embed[1024,256]
    const float* W1  = (const float*)d_in[3];   // [256,512]
    const float* b1  = (const float*)d_in[4];   // [512]
    const float* W2  = (const float*)d_in[5];   // [512,256]
    // d_in[6] = b2   : provably zero contribution, unused
    const float* W1g = (const float*)d_in[7];   // [512,512]
    const float* b1g = (const float*)d_in[8];   // [512]
    const float* W2g = (const float*)d_in[9];   // [512,256]
    // d_in[10] = b2g : unused
    float* ws  = (float*)d_ws;
    float* out = (float*)d_out;

    hipLaunchKernelGGL(hidden_colmean_kernel, dim3(288), dim3(256), 0, stream,
                       H, P, G, W1, b1, W1g, b1g, ws);
    hipLaunchKernelGGL(out_reduce_kernel,     dim3(256), dim3(256), 0, stream,
                       P, G, W2, W2g, ws);
    hipLaunchKernelGGL(final_kernel,          dim3(1),   dim3(256), 0, stream,
                       ws, out);
}

// Round 5
// 29.085 us; speedup vs baseline: 4.5346x; 1.6747x over previous
//
#include <hip/hip_runtime.h>

#define NR 1024
#define DX 256
#define HX 512

typedef __bf16 bf16x8 __attribute__((ext_vector_type(8)));
typedef float  f32x4  __attribute__((ext_vector_type(4)));

// ---- ws byte offsets (ws_size is 256 MiB per R4 fill evidence; we use ~7.3 MB)
#define B_CM    0u         // f32 [2][16][256] raw column sums per 64-row stripe (32 KB)
#define B_PART  32768u     // f32 [256] block partials
#define B_HBH   65536u     // ushort [1024][256]  H hi
#define B_HBL   589824u    // H lo
#define B_PBH   1114112u   // P hi
#define B_PBL   1638400u   // P lo
#define B_WT1   2162688u   // ushort [512][256]  W1^T bf16
#define B_WT1G  2424832u   // ushort [512][512]  W1g^T
#define B_WT2   2949120u   // ushort [256][512]  W2^T
#define B_WT2G  3211264u   // ushort [256][512]  W2g^T
#define B_H1H   3473408u   // ushort [1024][512] Hid1 hi
#define B_H1L   4521984u   // Hid1 lo
#define B_HGH   5570560u   // Hidg hi
#define B_HGL   6619136u   // Hidg lo

#define GLDS16(gp, lp) __builtin_amdgcn_global_load_lds(                     \
    (const __attribute__((address_space(1))) void*)(gp),                     \
    (__attribute__((address_space(3))) void*)(lp), 16, 0, 0)

__device__ __forceinline__ unsigned short bf16rne(float x) {
    unsigned int u = __float_as_uint(x);
    u = u + 0x7FFFu + ((u >> 16) & 1u);
    return (unsigned short)(u >> 16);
}
__device__ __forceinline__ float bf16f(unsigned short h) {
    return __uint_as_float(((unsigned int)h) << 16);
}

// ---------------------------------------------------------------------------
// Stage a 64x64-bf16 tile (row stride ld elems) into LDS [64][64] with 16B-slot
// swizzle slot' = slot ^ (row&7). global_load_lds writes linearly (base+lane*16),
// so the swizzle is applied by permuting the per-lane GLOBAL source (rule 21).
__device__ __forceinline__ void stage_bf16(const unsigned short* src, int r0, int c0,
                                           int ld, unsigned short* lds, int wv, int ln)
{
    const int gsl = (ln & 7) ^ ((ln >> 3) & 7);   // source 16B-slot (involution)
    #pragma unroll
    for (int i = 0; i < 2; ++i) {
        const int ins = wv * 2 + i;               // 1 KB chunk id 0..7 (8 rows each)
        const unsigned short* gp =
            src + (size_t)(r0 + ins * 8 + (ln >> 3)) * ld + c0 + gsl * 8;
        GLDS16(gp, lds + ins * 512);
    }
}

// Fragment read: 8 consecutive bf16 of (row, k=kc+8*(ln>>4)..+8), swizzled slot.
__device__ __forceinline__ uint4 ldsfrag(const unsigned short* lds, int row, int kc, int ln)
{
    const int slot = ((kc >> 3) + (ln >> 4)) ^ (row & 7);
    return *(const uint4*)((const char*)lds + row * 128 + slot * 16);
}

#define MFMA(a, b, c) __builtin_amdgcn_mfma_f32_16x16x32_bf16(                \
    __builtin_bit_cast(bf16x8, a), __builtin_bit_cast(bf16x8, b), c, 0, 0, 0)

// ---------------------------------------------------------------------------
// K0: prep. blocks [0,64): convert H/P -> bf16 hi/lo. [64,224): transpose+
// convert weights to [n][k] bf16 (hi only). [224,256): colmean raw partials.
__global__ __launch_bounds__(256) void prep_kernel(
    const float* __restrict__ H, const float* __restrict__ P, const float* __restrict__ G,
    const float* __restrict__ W1, const float* __restrict__ W1g,
    const float* __restrict__ W2, const float* __restrict__ W2g,
    char* __restrict__ wsb)
{
    __shared__ unsigned short T[64][72];
    const int bx = blockIdx.x, t = threadIdx.x;

    if (bx < 64) {
        const float* src = (bx < 32) ? H : P;
        unsigned short* dh = (unsigned short*)(wsb + ((bx < 32) ? B_HBH : B_PBH));
        unsigned short* dl = (unsigned short*)(wsb + ((bx < 32) ? B_HBL : B_PBL));
        const int base = (bx & 31) * 8192;
        #pragma unroll
        for (int k = 0; k < 8; ++k) {
            const int i = base + k * 1024 + t * 4;
            const float4 v = *(const float4*)(src + i);
            const unsigned short h0 = bf16rne(v.x), h1 = bf16rne(v.y),
                                 h2 = bf16rne(v.z), h3 = bf16rne(v.w);
            *(ushort4*)(dh + i) = make_ushort4(h0, h1, h2, h3);
            *(ushort4*)(dl + i) = make_ushort4(bf16rne(v.x - bf16f(h0)),
                                               bf16rne(v.y - bf16f(h1)),
                                               bf16rne(v.z - bf16f(h2)),
                                               bf16rne(v.w - bf16f(h3)));
        }
        return;
    }
    if (bx < 224) {
        const int bt = bx - 64;
        const float* src; unsigned short* dst; int ldn, ldk, k0, n0;
        if (bt < 32)       { src = W1;  dst = (unsigned short*)(wsb + B_WT1);
                             ldn = 512; ldk = 256; k0 = (bt >> 3) * 64;       n0 = (bt & 7) * 64; }
        else if (bt < 96)  { const int i = bt - 32;  src = W1g; dst = (unsigned short*)(wsb + B_WT1G);
                             ldn = 512; ldk = 512; k0 = (i >> 3) * 64;        n0 = (i & 7) * 64; }
        else if (bt < 128) { const int i = bt - 96;  src = W2;  dst = (unsigned short*)(wsb + B_WT2);
                             ldn = 256; ldk = 512; k0 = (i >> 2) * 64;        n0 = (i & 3) * 64; }
        else               { const int i = bt - 128; src = W2g; dst = (unsigned short*)(wsb + B_WT2G);
                             ldn = 256; ldk = 512; k0 = (i >> 2) * 64;        n0 = (i & 3) * 64; }
        const int cg = t & 15, rr = t >> 4;
        #pragma unroll
        for (int i = 0; i < 4; ++i) {
            const int r = i * 16 + rr;
            const float4 v = *(const float4*)(src + (size_t)(k0 + r) * ldn + n0 + cg * 4);
            T[cg * 4 + 0][r] = bf16rne(v.x); T[cg * 4 + 1][r] = bf16rne(v.y);
            T[cg * 4 + 2][r] = bf16rne(v.z); T[cg * 4 + 3][r] = bf16rne(v.w);
        }
        __syncthreads();
        #pragma unroll
        for (int i = 0; i < 4; ++i) {
            const int nr = i * 16 + rr;
            *(ushort4*)(dst + (size_t)(n0 + nr) * ldk + k0 + cg * 4) =
                *(const ushort4*)&T[nr][cg * 4];
        }
        return;
    }
    // colmean raw partials: 64 rows of P (cb<16) or G, column t
    const int cb = bx - 224;
    const float* M = (cb & 16) ? G : P;
    const float* p = M + (size_t)(cb & 15) * 64 * DX + t;
    float s0 = 0.f, s1 = 0.f, s2 = 0.f, s3 = 0.f;
    #pragma unroll 4
    for (int r = 0; r < 64; r += 4) {
        s0 += p[(r + 0) * DX]; s1 += p[(r + 1) * DX];
        s2 += p[(r + 2) * DX]; s3 += p[(r + 3) * DX];
    }
    ((float*)(wsb + B_CM))[((cb >> 4) * 16 + (cb & 15)) * 256 + t] = (s0 + s1) + (s2 + s3);
}

// ---------------------------------------------------------------------------
// K1: hidden GEMM, MFMA. 256 blocks: [0,128) MLP1, [128,256) MLPg.
// Block tile 64x64; 4 waves in 2x2; per-wave 32x32 (2x2 subtiles 16x16).
// acc += Ah*W + Al*W over K (256 / 512 via [H|P] concat). Epilogue +b1, relu,
// store as bf16 hi/lo.
__global__ __launch_bounds__(256) void gemm_hidden(
    const float* __restrict__ b1, const float* __restrict__ b1g, char* __restrict__ wsb)
{
    __shared__ unsigned short sAh[2][4096], sAl[2][4096], sW[2][4096];
    const int bx = blockIdx.x, t = threadIdx.x;
    const int mlp = bx >> 7, bi = bx & 127;
    const int m0 = (bi >> 3) * 64, n0 = (bi & 7) * 64;
    const int wv = t >> 6, ln = t & 63;
    const int wr = wv >> 1, wc = wv & 1;

    const unsigned short* hb_h = (const unsigned short*)(wsb + B_HBH);
    const unsigned short* hb_l = (const unsigned short*)(wsb + B_HBL);
    const unsigned short* pb_h = (const unsigned short*)(wsb + B_PBH);
    const unsigned short* pb_l = (const unsigned short*)(wsb + B_PBL);
    const unsigned short* wt   = (const unsigned short*)(wsb + (mlp ? B_WT1G : B_WT1));
    const int ldk = mlp ? 512 : 256;
    const int nc  = mlp ? 8 : 4;

    stage_bf16(hb_h, m0, 0, 256, sAh[0], wv, ln);
    stage_bf16(hb_l, m0, 0, 256, sAl[0], wv, ln);
    stage_bf16(wt,   n0, 0, ldk, sW[0],  wv, ln);
    asm volatile("s_waitcnt vmcnt(0)" ::: "memory");
    __syncthreads();

    f32x4 zero = {0.f, 0.f, 0.f, 0.f};
    f32x4 acc[2][2] = {{zero, zero}, {zero, zero}};

    int buf = 0;
    for (int c = 0; c < nc; ++c) {
        if (c + 1 < nc) {
            const int cn = c + 1;
            const unsigned short* ah = (mlp && cn >= 4) ? pb_h : hb_h;
            const unsigned short* al = (mlp && cn >= 4) ? pb_l : hb_l;
            stage_bf16(ah, m0, (cn & 3) * 64, 256, sAh[buf ^ 1], wv, ln);
            stage_bf16(al, m0, (cn & 3) * 64, 256, sAl[buf ^ 1], wv, ln);
            stage_bf16(wt, n0, cn * 64,       ldk, sW[buf ^ 1],  wv, ln);
        }
        #pragma unroll
        for (int kc = 0; kc < 64; kc += 32) {
            uint4 fh[2], fl[2], fw[2];
            #pragma unroll
            for (int s = 0; s < 2; ++s) {
                const int ra = 32 * wr + 16 * s + (ln & 15);
                fh[s] = ldsfrag(sAh[buf], ra, kc, ln);
                fl[s] = ldsfrag(sAl[buf], ra, kc, ln);
                fw[s] = ldsfrag(sW[buf], 32 * wc + 16 * s + (ln & 15), kc, ln);
            }
            #pragma unroll
            for (int sr = 0; sr < 2; ++sr)
                #pragma unroll
                for (int sc = 0; sc < 2; ++sc) {
                    acc[sr][sc] = MFMA(fh[sr], fw[sc], acc[sr][sc]);
                    acc[sr][sc] = MFMA(fl[sr], fw[sc], acc[sr][sc]);
                }
        }
        asm volatile("s_waitcnt vmcnt(0)" ::: "memory");
        __syncthreads();
        buf ^= 1;
    }

    const float* bb = mlp ? b1g : b1;
    unsigned short* oh = (unsigned short*)(wsb + (mlp ? B_HGH : B_H1H));
    unsigned short* ol = (unsigned short*)(wsb + (mlp ? B_HGL : B_H1L));
    #pragma unroll
    for (int sc = 0; sc < 2; ++sc) {
        const int C = n0 + 32 * wc + 16 * sc + (ln & 15);
        const float bv = bb[C];
        #pragma unroll
        for (int sr = 0; sr < 2; ++sr)
            #pragma unroll
            for (int r = 0; r < 4; ++r) {
                const int R = m0 + 32 * wr + 16 * sr + 4 * (ln >> 4) + r;
                float v = fmaxf(acc[sr][sc][r] + bv, 0.f);
                const unsigned short h = bf16rne(v);
                oh[(size_t)R * 512 + C] = h;
                ol[(size_t)R * 512 + C] = bf16rne(v - bf16f(h));
            }
    }
}

// ---------------------------------------------------------------------------
// K2: mu = Hid @ W2 (b2 contributes exactly 0 against centered Y), dotted on
// the fly with (Y - colmean(Y)). 256 blocks: [mlp][ksplit][16 rowtiles][4 col].
__global__ __launch_bounds__(256) void gemm_out(
    const float* __restrict__ P, const float* __restrict__ G, char* __restrict__ wsb)
{
    __shared__ unsigned short sAh[2][4096], sAl[2][4096], sW[2][4096];
    __shared__ float red[256];
    const int bx = blockIdx.x, t = threadIdx.x;
    const int mlp = bx >> 7;
    const int ks  = (bx >> 6) & 1;
    const int m0  = ((bx >> 2) & 15) * 64;
    const int n0  = (bx & 3) * 64;
    const int wv = t >> 6, ln = t & 63;
    const int wr = wv >> 1, wc = wv & 1;

    const unsigned short* ha = (const unsigned short*)(wsb + (mlp ? B_HGH : B_H1H));
    const unsigned short* la = (const unsigned short*)(wsb + (mlp ? B_HGL : B_H1L));
    const unsigned short* wt = (const unsigned short*)(wsb + (mlp ? B_WT2G : B_WT2));
    const float* Y  = mlp ? G : P;
    const float* cm = (const float*)(wsb + B_CM) + mlp * 4096;
    const int kb = ks * 256;

    stage_bf16(ha, m0, kb, 512, sAh[0], wv, ln);
    stage_bf16(la, m0, kb, 512, sAl[0], wv, ln);
    stage_bf16(wt, n0, kb, 512, sW[0],  wv, ln);
    asm volatile("s_waitcnt vmcnt(0)" ::: "memory");
    __syncthreads();

    f32x4 zero = {0.f, 0.f, 0.f, 0.f};
    f32x4 acc[2][2] = {{zero, zero}, {zero, zero}};

    int buf = 0;
    for (int c = 0; c < 4; ++c) {
        if (c + 1 < 4) {
            const int colk = kb + (c + 1) * 64;
            stage_bf16(ha, m0, colk, 512, sAh[buf ^ 1], wv, ln);
            stage_bf16(la, m0, colk, 512, sAl[buf ^ 1], wv, ln);
            stage_bf16(wt, n0, colk, 512, sW[buf ^ 1],  wv, ln);
        }
        #pragma unroll
        for (int kc = 0; kc < 64; kc += 32) {
            uint4 fh[2], fl[2], fw[2];
            #pragma unroll
            for (int s = 0; s < 2; ++s) {
                const int ra = 32 * wr + 16 * s + (ln & 15);
                fh[s] = ldsfrag(sAh[buf], ra, kc, ln);
                fl[s] = ldsfrag(sAl[buf], ra, kc, ln);
                fw[s] = ldsfrag(sW[buf], 32 * wc + 16 * s + (ln & 15), kc, ln);
            }
            #pragma unroll
            for (int sr = 0; sr < 2; ++sr)
                #pragma unroll
                for (int sc = 0; sc < 2; ++sc) {
                    acc[sr][sc] = MFMA(fh[sr], fw[sc], acc[sr][sc]);
                    acc[sr][sc] = MFMA(fl[sr], fw[sc], acc[sr][sc]);
                }
        }
        asm volatile("s_waitcnt vmcnt(0)" ::: "memory");
        __syncthreads();
        buf ^= 1;
    }

    float part = 0.f;
    #pragma unroll
    for (int sc = 0; sc < 2; ++sc) {
        const int C = n0 + 32 * wc + 16 * sc + (ln & 15);
        float s = 0.f;
        #pragma unroll
        for (int st = 0; st < 16; ++st) s += cm[st * 256 + C];
        const float e = s * (1.0f / NR);
        #pragma unroll
        for (int sr = 0; sr < 2; ++sr)
            #pragma unroll
            for (int r = 0; r < 4; ++r) {
                const int R = m0 + 32 * wr + 16 * sr + 4 * (ln >> 4) + r;
                part += acc[sr][sc][r] * (Y[(size_t)R * DX + C] - e);
            }
    }
    red[t] = part;
    __syncthreads();
    #pragma unroll
    for (int sft = 128; sft > 0; sft >>= 1) {
        if (t < sft) red[t] += red[t + sft];
        __syncthreads();
    }
    if (t == 0) ((float*)(wsb + B_PART))[bx] = red[0];
}

// ---------------------------------------------------------------------------
// K3: final reduce of 256 partials in double, scale by 1/N.
__global__ __launch_bounds__(256) void final_kernel(const char* __restrict__ wsb,
                                                    float* __restrict__ out)
{
    const int t = threadIdx.x;
    __shared__ double red[256];
    red[t] = (double)((const float*)(wsb + B_PART))[t];
    __syncthreads();
    #pragma unroll
    for (int s = 128; s > 0; s >>= 1) {
        if (t < s) red[t] += red[t + s];
        __syncthreads();
    }
    if (t == 0) out[0] = (float)(red[0] * (1.0 / NR));
}

// ---------------------------------------------------------------------------
extern "C" void kernel_launch(void* const* d_in, const int* in_sizes, int n_in,
                              void* d_out, int out_size, void* d_ws, size_t ws_size,
                              hipStream_t stream)
{
    const float* H   = (const float*)d_in[0];
    const float* P   = (const float*)d_in[1];
    const float* G   = (const float*)d_in[2];
    const float* W1  = (const float*)d_in[3];
    const float* b1  = (const float*)d_in[4];
    const float* W2  = (const float*)d_in[5];
    // d_in[6] = b2: provably zero contribution
    const float* W1g = (const float*)d_in[7];
    const float* b1g = (const float*)d_in[8];
    const float* W2g = (const float*)d_in[9];
    // d_in[10] = b2g: unused
    char* wsb = (char*)d_ws;
    float* out = (float*)d_out;

    hipLaunchKernelGGL(prep_kernel,  dim3(256), dim3(256), 0, stream,
                       H, P, G, W1, W1g, W2, W2g, wsb);
    hipLaunchKernelGGL(gemm_hidden,  dim3(256), dim3(256), 0, stream, b1, b1g, wsb);
    hipLaunchKernelGGL(gemm_out,     dim3(256), dim3(256), 0, stream, P, G, wsb);
    hipLaunchKernelGGL(final_kernel, dim3(1),   dim3(256), 0, stream, wsb, out);
}